// Round 13
// baseline (249.900 us; speedup 1.0000x reference)
//
#include <hip/hip_runtime.h>

#define B_  4
#define C_  512
#define CQ_ 64
#define N_  4096
#define LOG2E 1.44269504088896f

typedef _Float16 half8 __attribute__((ext_vector_type(8)));
typedef _Float16 half4 __attribute__((ext_vector_type(4)));
typedef float    f32x4 __attribute__((ext_vector_type(4)));

// async global->LDS, 16B per lane; LDS dest = wave-uniform base + lane*16
__device__ __forceinline__ void g2l16(const void* g, void* l) {
  __builtin_amdgcn_global_load_lds(
      (const __attribute__((address_space(1))) void*)g,
      (__attribute__((address_space(3))) void*)l, 16, 0, 0);
}

// ---------------------------------------------------------------------------
// Kernel 0: W -> fp16 (Wq rows pre-scaled by log2e).  Wh[640][512].
// ---------------------------------------------------------------------------
__global__ __launch_bounds__(256) void wcvt_kernel(
    const float* __restrict__ Wq, const float* __restrict__ Wk,
    const float* __restrict__ Wv, _Float16* __restrict__ Wh)
{
  const int row = blockIdx.x;
  const float* src;
  float s = 1.0f;
  if (row < 64)       { src = Wq + (size_t)row * C_; s = LOG2E; }
  else if (row < 128) { src = Wk + (size_t)(row - 64) * C_; }
  else                { src = Wv + (size_t)(row - 128) * C_; }
  for (int c = threadIdx.x; c < C_; c += 256)
    Wh[(size_t)row * C_ + c] = (_Float16)(src[c] * s);
}

// ---------------------------------------------------------------------------
// Kernel 1: fused QKV projection, x staged ONCE per block (unchanged).
// ---------------------------------------------------------------------------
__global__ __launch_bounds__(256) void proj_kernel(
    const float* __restrict__ x, const _Float16* __restrict__ Wh,
    _Float16* __restrict__ Qh, _Float16* __restrict__ Kh, _Float16* __restrict__ Vh)
{
  __shared__ _Float16 xs[32][520];   // 33.3 KB

  const int tid = threadIdx.x;
  const int wid = tid >> 6, lane = tid & 63, ln = lane & 15, lh = lane >> 4;

  const int wg = (blockIdx.x & 7) * 64 + (blockIdx.x >> 3);
  const int b  = wg >> 7;
  const int n0 = (wg & 127) * 32;

  {
    const int nn = (tid & 7) * 4;
    const int c0 = tid >> 3;
    #pragma unroll 4
    for (int cc = 0; cc < 16; ++cc) {
      const int c = cc * 32 + c0;
      f32x4 v = *(const f32x4*)&x[((size_t)b * C_ + c) * N_ + n0 + nn];
      #pragma unroll
      for (int u = 0; u < 4; ++u) xs[nn + u][c] = (_Float16)v[u];
    }
  }
  __syncthreads();

  for (int chT = 0; chT < 10; ++chT) {
    f32x4 acc[2] = {};
    const _Float16* wrow = Wh + (size_t)(chT * 64 + wid * 16 + ln) * C_;

    #pragma unroll 4
    for (int kt = 0; kt < C_; kt += 32) {
      half8 a = *(const half8*)&wrow[kt + lh * 8];
      #pragma unroll
      for (int ct = 0; ct < 2; ++ct) {
        half8 bf = *(const half8*)&xs[ct * 16 + ln][kt + lh * 8];
        acc[ct] = __builtin_amdgcn_mfma_f32_16x16x32_f16(a, bf, acc[ct], 0, 0, 0);
      }
    }

    #pragma unroll
    for (int ct = 0; ct < 2; ++ct) {
      const int n = n0 + ct * 16 + ln;
      #pragma unroll
      for (int j = 0; j < 4; ++j) {
        const int chL = wid * 16 + lh * 4 + j;
        const _Float16 v = (_Float16)acc[ct][j];
        if (chT == 0)      Qh[((size_t)b * N_ + n) * CQ_ + chL] = v;
        else if (chT == 1) Kh[((size_t)b * N_ + n) * CQ_ + chL] = v;
        else               Vh[((size_t)b * C_ + (chT - 2) * 64 + chL) * N_ + n] = v;
      }
    }
  }
}

// ---------------------------------------------------------------------------
// Kernel 2: exact per-row MAX only (log2 domain).  The softmax denominator
// is accumulated in pwrite (which computes every exp2 anyway) -> removes the
// serial online (m,s) chain and 67M exp2 ops from this kernel.
// Swapped mfma(K,Q), same fragment chain as pwrite so e-m <= ~0 there.
// ---------------------------------------------------------------------------
__global__ __launch_bounds__(512, 2) void stats_kernel(
    const _Float16* __restrict__ Qh, const _Float16* __restrict__ Kh,
    float* __restrict__ m_g)
{
  __shared__ float Ms[8][64];

  const int tid = threadIdx.x;
  const int wid = tid >> 6, lane = tid & 63, ln = lane & 15, lh = lane >> 4;
  const int b  = blockIdx.x >> 6;
  const int qb = (blockIdx.x & 63) * 64;

  half8 qf[4][2];
  #pragma unroll
  for (int rt = 0; rt < 4; ++rt)
    #pragma unroll
    for (int h = 0; h < 2; ++h)
      qf[rt][h] = *(const half8*)&Qh[((size_t)b * N_ + qb + rt * 16 + ln) * CQ_ + h * 32 + lh * 8];

  float mx[4] = {-3.0e38f, -3.0e38f, -3.0e38f, -3.0e38f};

  const _Float16* kp = Kh + ((size_t)b * N_ + wid * 16 + ln) * CQ_ + lh * 8;

  for (int it = 0; it < 32; ++it) {
    const _Float16* kq = kp + (size_t)(it * 128) * CQ_;
    half8 k0 = *(const half8*)kq;
    half8 k1 = *(const half8*)(kq + 32);
    #pragma unroll
    for (int rt = 0; rt < 4; ++rt) {
      f32x4 e = {};
      e = __builtin_amdgcn_mfma_f32_16x16x32_f16(k0, qf[rt][0], e, 0, 0, 0);
      e = __builtin_amdgcn_mfma_f32_16x16x32_f16(k1, qf[rt][1], e, 0, 0, 0);
      mx[rt] = fmaxf(mx[rt], fmaxf(fmaxf(e[0], e[1]), fmaxf(e[2], e[3])));
    }
  }

  #pragma unroll
  for (int rt = 0; rt < 4; ++rt) {
    float m = mx[rt];
    m = fmaxf(m, __shfl_xor(m, 16));
    m = fmaxf(m, __shfl_xor(m, 32));
    if (lane < 16) Ms[wid][rt * 16 + lane] = m;
  }
  __syncthreads();
  if (tid < 64) {
    float m = Ms[0][tid];
    #pragma unroll
    for (int w = 1; w < 8; ++w) m = fmaxf(m, Ms[w][tid]);
    m_g[(size_t)b * N_ + qb + tid] = m;
  }
}

// ---------------------------------------------------------------------------
// Kernel 3: P-writer.  P[bz][q][m] = exp2(e - m_q)  (fp16, UNnormalized, <=1).
// Also writes deterministic partial denominators Lp[mb][b][q] (sum over this
// block's 256 m).  MFMA results -> padded LDS -> coalesced 16B stores.
// ---------------------------------------------------------------------------
__global__ __launch_bounds__(256) void pwrite_kernel(
    const _Float16* __restrict__ Qh, const _Float16* __restrict__ Kh,
    const float* __restrict__ m_g, float* __restrict__ Lp,
    _Float16* __restrict__ P, int b0)
{
  __shared__ _Float16 Pl[64 * 260];
  __shared__ float    Ls[4][64];

  const int tid = threadIdx.x;
  const int wid = tid >> 6, lane = tid & 63, ln = lane & 15, lh = lane >> 4;
  const int mb = blockIdx.x * 256;
  const int qb = blockIdx.y * 64;
  const int bz = blockIdx.z;
  const int b  = b0 + bz;

  float m_l[4];
  #pragma unroll
  for (int rt = 0; rt < 4; ++rt)
    m_l[rt] = m_g[(size_t)b * N_ + qb + rt * 16 + ln];

  half8 qf[4][2];
  #pragma unroll
  for (int rt = 0; rt < 4; ++rt)
    #pragma unroll
    for (int h = 0; h < 2; ++h)
      qf[rt][h] = *(const half8*)&Qh[((size_t)b * N_ + qb + rt * 16 + ln) * CQ_ + h * 32 + lh * 8];

  half8 kf[4][2];
  #pragma unroll
  for (int ms = 0; ms < 4; ++ms)
    #pragma unroll
    for (int h = 0; h < 2; ++h)
      kf[ms][h] = *(const half8*)&Kh[((size_t)b * N_ + mb + wid * 64 + ms * 16 + ln) * CQ_ + h * 32 + lh * 8];

  float psum[4] = {0.f, 0.f, 0.f, 0.f};

  #pragma unroll
  for (int ms = 0; ms < 4; ++ms) {
    #pragma unroll
    for (int rt = 0; rt < 4; ++rt) {
      f32x4 e = {};
      e = __builtin_amdgcn_mfma_f32_16x16x32_f16(kf[ms][0], qf[rt][0], e, 0, 0, 0);
      e = __builtin_amdgcn_mfma_f32_16x16x32_f16(kf[ms][1], qf[rt][1], e, 0, 0, 0);
      half4 pv;
      #pragma unroll
      for (int j = 0; j < 4; ++j) {
        const float p = exp2f(e[j] - m_l[rt]);
        psum[rt] += p;
        pv[j] = (_Float16)p;
      }
      *(half4*)&Pl[(rt * 16 + ln) * 260 + wid * 64 + ms * 16 + lh * 4] = pv;
    }
  }

  // reduce psum over the 4 lh groups (same q, different m)
  #pragma unroll
  for (int rt = 0; rt < 4; ++rt) {
    psum[rt] += __shfl_xor(psum[rt], 16);
    psum[rt] += __shfl_xor(psum[rt], 32);
    if (lane < 16) Ls[wid][rt * 16 + lane] = psum[rt];
  }
  __syncthreads();

  if (tid < 64) {
    const float s = Ls[0][tid] + Ls[1][tid] + Ls[2][tid] + Ls[3][tid];
    Lp[((size_t)blockIdx.x * B_ + b) * N_ + qb + tid] = s;
  }

  const int row = tid >> 2;
  const int cb  = (tid & 3) * 8;
  #pragma unroll
  for (int i = 0; i < 8; ++i) {
    half8 v = *(const half8*)&Pl[row * 260 + cb + i * 32];
    *(half8*)&P[((size_t)bz * N_ + qb + row) * N_ + mb + cb + i * 32] = v;
  }
}

// ---------------------------------------------------------------------------
// Kernel 3b: fold partial denominators -> il = 1/sum (deterministic).
// ---------------------------------------------------------------------------
__global__ __launch_bounds__(256) void lred_kernel(
    const float* __restrict__ Lp, float* __restrict__ il_g, int b0)
{
  const int bz = blockIdx.x >> 4;
  const int q  = (blockIdx.x & 15) * 256 + threadIdx.x;
  const int b  = b0 + bz;
  float s = 0.f;
  #pragma unroll
  for (int mb = 0; mb < 16; ++mb)
    s += Lp[((size_t)mb * B_ + b) * N_ + q];
  il_g[(size_t)b * N_ + q] = 1.0f / s;
}

// ---------------------------------------------------------------------------
// Kernel 4: PV GEMM, counted-vmcnt triple-buffer (T3+T4) + T5 setprio.
// out[b][d][n] = g * (V . P'^T) * il[n] + x.
// Tile 256d x 128n, BK=64, 512 thr (8 waves 4x2; wave = 64d x 64n).
// Per iter: vmcnt(6) -> barrier -> stage(t+2) [issued EARLY] -> ds_read ->
// setprio(1) 32 MFMAs setprio(0).  vmcnt never drains until the tail.
// ---------------------------------------------------------------------------
__global__ __launch_bounds__(512) void pv_kernel(
    const float* __restrict__ x, const _Float16* __restrict__ Vh,
    const _Float16* __restrict__ P, const float* __restrict__ il_g,
    const float* __restrict__ gamma, float* __restrict__ out, int b0, int nwg)
{
  __shared__ _Float16 As[3][256 * 64];   // 32 KB x3
  __shared__ _Float16 Bs[3][128 * 64];   // 16 KB x3

  const int tid = threadIdx.x;
  const int wid = tid >> 6, lane = tid & 63, ln = lane & 15, lh = lane >> 4;

  const int q8 = nwg >> 3;
  const int wg = (blockIdx.x & 7) * q8 + (blockIdx.x >> 3);
  const int dt = wg & 1;
  const int nt = (wg >> 1) & 31;
  const int bz = wg >> 6;
  const int b  = b0 + bz;
  const int d0 = dt * 256, n0 = nt * 128;

  const _Float16* Ab = Vh + ((size_t)b * C_ + d0) * N_;
  const _Float16* Bb = P  + ((size_t)bz * N_ + n0) * N_;

  const int srow   = lane >> 3;
  const int schunk = lane & 7;
  const _Float16* aSrc[4];
  const _Float16* bSrc[2];
  #pragma unroll
  for (int r = 0; r < 4; ++r) {
    const int row = r * 64 + wid * 8 + srow;
    aSrc[r] = Ab + (size_t)row * N_ + ((schunk ^ (row & 7)) << 3);
  }
  #pragma unroll
  for (int r = 0; r < 2; ++r) {
    const int row = r * 64 + wid * 8 + srow;
    bSrc[r] = Bb + (size_t)row * N_ + ((schunk ^ (row & 7)) << 3);
  }

  auto stage = [&](int buf, int t) {
    const int m0 = t << 6;
    #pragma unroll
    for (int r = 0; r < 4; ++r)
      g2l16(aSrc[r] + m0, (char*)&As[buf][0] + r * 8192 + wid * 1024);
    #pragma unroll
    for (int r = 0; r < 2; ++r)
      g2l16(bSrc[r] + m0, (char*)&Bs[buf][0] + r * 8192 + wid * 1024);
  };

  const int wr = wid >> 1, wc = wid & 1;   // wave = 64d x 64n
  f32x4 acc[4][4] = {};
  const int swl = ln & 7;

  stage(0, 0);
  stage(1, 1);                             // 12 loads in flight

  for (int t = 0; t < 64; ++t) {
    if (t < 63) { asm volatile("s_waitcnt vmcnt(6)" ::: "memory"); }
    else        { asm volatile("s_waitcnt vmcnt(0)" ::: "memory"); }
    __builtin_amdgcn_s_barrier();
    __builtin_amdgcn_sched_barrier(0);

    if (t < 62) stage((t + 2) % 3, t + 2);   // issue prefetch EARLY

    const int buf = t % 3;
    const _Float16* Ar = &As[buf][0];
    const _Float16* Br = &Bs[buf][0];

    half8 a[4][2], bq[4][2];
    #pragma unroll
    for (int ft = 0; ft < 4; ++ft) {
      const int row = wr * 64 + ft * 16 + ln;
      #pragma unroll
      for (int kk = 0; kk < 2; ++kk)
        a[ft][kk] = *(const half8*)&Ar[row * 64 + ((((kk << 2) | lh) ^ swl) << 3)];
    }
    #pragma unroll
    for (int gt = 0; gt < 4; ++gt) {
      const int row = wc * 64 + gt * 16 + ln;
      #pragma unroll
      for (int kk = 0; kk < 2; ++kk)
        bq[gt][kk] = *(const half8*)&Br[row * 64 + ((((kk << 2) | lh) ^ swl) << 3)];
    }

    __builtin_amdgcn_s_setprio(1);
    #pragma unroll
    for (int kk = 0; kk < 2; ++kk)
      #pragma unroll
      for (int ft = 0; ft < 4; ++ft)
        #pragma unroll
        for (int gt = 0; gt < 4; ++gt)
          acc[ft][gt] = __builtin_amdgcn_mfma_f32_16x16x32_f16(a[ft][kk], bq[gt][kk], acc[ft][gt], 0, 0, 0);
    __builtin_amdgcn_s_setprio(0);
  }

  // epilogue: il per n column, then fused residual
  const float g = gamma[0];
  float il[4];
  #pragma unroll
  for (int gt = 0; gt < 4; ++gt)
    il[gt] = il_g[(size_t)b * N_ + n0 + wc * 64 + gt * 16 + ln];

  #pragma unroll
  for (int ft = 0; ft < 4; ++ft) {
    #pragma unroll
    for (int gt = 0; gt < 4; ++gt) {
      const float gi = g * il[gt];
      #pragma unroll
      for (int j = 0; j < 4; ++j) {
        const int d = d0 + wr * 64 + ft * 16 + lh * 4 + j;
        const int n = n0 + wc * 64 + gt * 16 + ln;
        const size_t idx = ((size_t)b * C_ + d) * N_ + n;
        out[idx] = gi * acc[ft][gt][j] + x[idx];
      }
    }
  }
}

extern "C" void kernel_launch(void* const* d_in, const int* in_sizes, int n_in,
                              void* d_out, int out_size, void* d_ws, size_t ws_size,
                              hipStream_t stream) {
  const float* x     = (const float*)d_in[0];
  const float* Wq    = (const float*)d_in[1];
  const float* Wk    = (const float*)d_in[2];
  const float* Wv    = (const float*)d_in[3];
  const float* gamma = (const float*)d_in[4];
  float* out = (float*)d_out;

  _Float16* Qh = (_Float16*)d_ws;                        // 2 MB
  _Float16* Kh = Qh + (size_t)B_ * N_ * CQ_;             // 2 MB
  _Float16* Vh = Kh + (size_t)B_ * N_ * CQ_;             // 16.8 MB
  float* m_g   = (float*)(Vh + (size_t)B_ * C_ * N_);    // 64 KB
  float* il_g  = m_g + (size_t)B_ * N_;                  // 64 KB
  float* Lp    = il_g + (size_t)B_ * N_;                 // 16*B*N f32 = 1 MB
  _Float16* Wh = (_Float16*)(Lp + (size_t)16 * B_ * N_); // 0.66 MB
  _Float16* P  = Wh + (size_t)640 * C_;

  const size_t fixed = (size_t)((char*)P - (char*)d_ws);
  const int nb = (ws_size >= fixed + (size_t)B_ * N_ * N_ * sizeof(_Float16)) ? 4 : 2;

  wcvt_kernel<<<dim3(640), 256, 0, stream>>>(Wq, Wk, Wv, Wh);
  proj_kernel<<<dim3(512), 256, 0, stream>>>(x, Wh, Qh, Kh, Vh);
  stats_kernel<<<dim3(256), 512, 0, stream>>>(Qh, Kh, m_g);

  for (int b0 = 0; b0 < B_; b0 += nb) {
    pwrite_kernel<<<dim3(16, 64, nb), 256, 0, stream>>>(Qh, Kh, m_g, Lp, P, b0);
    lred_kernel<<<dim3(nb * 16), 256, 0, stream>>>(Lp, il_g, b0);
    pv_kernel<<<dim3(nb * 64), 512, 0, stream>>>(x, Vh, P, il_g, gamma, out, b0, nb * 64);
  }
}

// Round 14
// 185.580 us; speedup vs baseline: 1.3466x; 1.3466x over previous
//
#include <hip/hip_runtime.h>

#define B_  4
#define C_  512
#define CQ_ 64
#define N_  4096
#define LOG2E 1.44269504088896f

typedef _Float16 half8 __attribute__((ext_vector_type(8)));
typedef _Float16 half4 __attribute__((ext_vector_type(4)));
typedef float    f32x4 __attribute__((ext_vector_type(4)));

// async global->LDS, 16B per lane; LDS dest = wave-uniform base + lane*16
__device__ __forceinline__ void g2l16(const void* g, void* l) {
  __builtin_amdgcn_global_load_lds(
      (const __attribute__((address_space(1))) void*)g,
      (__attribute__((address_space(3))) void*)l, 16, 0, 0);
}

// ---------------------------------------------------------------------------
// Kernel 0: W -> fp16 (Wq rows pre-scaled by log2e).  Wh[640][512].
// ---------------------------------------------------------------------------
__global__ __launch_bounds__(256) void wcvt_kernel(
    const float* __restrict__ Wq, const float* __restrict__ Wk,
    const float* __restrict__ Wv, _Float16* __restrict__ Wh)
{
  const int row = blockIdx.x;
  const float* src;
  float s = 1.0f;
  if (row < 64)       { src = Wq + (size_t)row * C_; s = LOG2E; }
  else if (row < 128) { src = Wk + (size_t)(row - 64) * C_; }
  else                { src = Wv + (size_t)(row - 128) * C_; }
  for (int c = threadIdx.x; c < C_; c += 256)
    Wh[(size_t)row * C_ + c] = (_Float16)(src[c] * s);
}

// ---------------------------------------------------------------------------
// Kernel 1: fused QKV projection, x staged ONCE per block.
// Block = (b, 32 n); x tile -> padded LDS; loop 10 chTiles vs fp16 Wh (L2).
// V output tiles staged through a small LDS buffer -> coalesced 64B-row
// half8 stores (was: scalar 2B scattered stores).
// ---------------------------------------------------------------------------
__global__ __launch_bounds__(256) void proj_kernel(
    const float* __restrict__ x, const _Float16* __restrict__ Wh,
    _Float16* __restrict__ Qh, _Float16* __restrict__ Kh, _Float16* __restrict__ Vh)
{
  __shared__ _Float16 xs[32][520];   // 33.3 KB
  __shared__ _Float16 vs[64][40];    // 5.1 KB V-store staging

  const int tid = threadIdx.x;
  const int wid = tid >> 6, lane = tid & 63, ln = lane & 15, lh = lane >> 4;

  // bijective XCD swizzle: 512 blocks, 64 consecutive wg per XCD
  const int wg = (blockIdx.x & 7) * 64 + (blockIdx.x >> 3);
  const int b  = wg >> 7;
  const int n0 = (wg & 127) * 32;

  // stage x tile (fp32 -> fp16, transpose to [n][c])
  {
    const int nn = (tid & 7) * 4;
    const int c0 = tid >> 3;
    #pragma unroll 4
    for (int cc = 0; cc < 16; ++cc) {
      const int c = cc * 32 + c0;
      f32x4 v = *(const f32x4*)&x[((size_t)b * C_ + c) * N_ + n0 + nn];
      #pragma unroll
      for (int u = 0; u < 4; ++u) xs[nn + u][c] = (_Float16)v[u];
    }
  }
  __syncthreads();

  for (int chT = 0; chT < 10; ++chT) {
    f32x4 acc[2] = {};
    const _Float16* wrow = Wh + (size_t)(chT * 64 + wid * 16 + ln) * C_;

    #pragma unroll 4
    for (int kt = 0; kt < C_; kt += 32) {
      half8 a = *(const half8*)&wrow[kt + lh * 8];
      #pragma unroll
      for (int ct = 0; ct < 2; ++ct) {
        half8 bf = *(const half8*)&xs[ct * 16 + ln][kt + lh * 8];
        acc[ct] = __builtin_amdgcn_mfma_f32_16x16x32_f16(a, bf, acc[ct], 0, 0, 0);
      }
    }

    if (chT < 2) {
      #pragma unroll
      for (int ct = 0; ct < 2; ++ct) {
        const int n = n0 + ct * 16 + ln;
        #pragma unroll
        for (int j = 0; j < 4; ++j) {
          const int chL = wid * 16 + lh * 4 + j;
          const _Float16 v = (_Float16)acc[ct][j];
          if (chT == 0) Qh[((size_t)b * N_ + n) * CQ_ + chL] = v;
          else          Kh[((size_t)b * N_ + n) * CQ_ + chL] = v;
        }
      }
    } else {
      __syncthreads();   // prior vs reads (previous chT store) complete
      #pragma unroll
      for (int ct = 0; ct < 2; ++ct)
        #pragma unroll
        for (int j = 0; j < 4; ++j)
          vs[wid * 16 + lh * 4 + j][ct * 16 + ln] = (_Float16)acc[ct][j];
      __syncthreads();
      const int row = tid >> 2, cb = (tid & 3) * 8;
      *(half8*)&Vh[((size_t)b * C_ + (chT - 2) * 64 + row) * N_ + n0 + cb] =
          *(const half8*)&vs[row][cb];
    }
  }
}

// ---------------------------------------------------------------------------
// Kernel 2: exact softmax stats (log2 domain): per-row max m and 1/l.
// Swapped mfma(K,Q), online (m,s) per thread, no loop barriers.
// K register-prefetched one iteration ahead (hide L2 latency under the
// MFMA + exp chain).  Same 2-MFMA chain as pwrite, so e-m <= ~0 there.
// ---------------------------------------------------------------------------
__global__ __launch_bounds__(512, 2) void stats_kernel(
    const _Float16* __restrict__ Qh, const _Float16* __restrict__ Kh,
    float* __restrict__ m_g, float* __restrict__ il_g)
{
  __shared__ float Ms[8][64];
  __shared__ float Ss[8][64];

  const int tid = threadIdx.x;
  const int wid = tid >> 6, lane = tid & 63, ln = lane & 15, lh = lane >> 4;
  const int b  = blockIdx.x >> 6;
  const int qb = (blockIdx.x & 63) * 64;

  half8 qf[4][2];
  #pragma unroll
  for (int rt = 0; rt < 4; ++rt)
    #pragma unroll
    for (int h = 0; h < 2; ++h)
      qf[rt][h] = *(const half8*)&Qh[((size_t)b * N_ + qb + rt * 16 + ln) * CQ_ + h * 32 + lh * 8];

  float mx[4] = {-3.0e38f, -3.0e38f, -3.0e38f, -3.0e38f};
  float sm[4] = {0.f, 0.f, 0.f, 0.f};

  const _Float16* kp = Kh + ((size_t)b * N_ + wid * 16 + ln) * CQ_ + lh * 8;

  half8 k0 = *(const half8*)kp;
  half8 k1 = *(const half8*)(kp + 32);

  for (int it = 0; it < 32; ++it) {
    half8 kn0, kn1;
    if (it < 31) {
      const _Float16* kq = kp + (size_t)((it + 1) * 128) * CQ_;
      kn0 = *(const half8*)kq;
      kn1 = *(const half8*)(kq + 32);
    }
    #pragma unroll
    for (int rt = 0; rt < 4; ++rt) {
      f32x4 e = {};
      e = __builtin_amdgcn_mfma_f32_16x16x32_f16(k0, qf[rt][0], e, 0, 0, 0);
      e = __builtin_amdgcn_mfma_f32_16x16x32_f16(k1, qf[rt][1], e, 0, 0, 0);
      const float m1 = fmaxf(fmaxf(e[0], e[1]), fmaxf(e[2], e[3]));
      const float mn = fmaxf(mx[rt], m1);
      sm[rt] = sm[rt] * exp2f(mx[rt] - mn)
             + exp2f(e[0] - mn) + exp2f(e[1] - mn)
             + exp2f(e[2] - mn) + exp2f(e[3] - mn);
      mx[rt] = mn;
    }
    k0 = kn0; k1 = kn1;
  }

  #pragma unroll
  for (int rt = 0; rt < 4; ++rt) {
    float m = mx[rt], s = sm[rt];
    #pragma unroll
    for (int mask = 16; mask <= 32; mask <<= 1) {
      const float om = __shfl_xor(m, mask);
      const float os = __shfl_xor(s, mask);
      const float mn = fmaxf(m, om);
      s = s * exp2f(m - mn) + os * exp2f(om - mn);
      m = mn;
    }
    if (lane < 16) { Ms[wid][rt * 16 + lane] = m; Ss[wid][rt * 16 + lane] = s; }
  }
  __syncthreads();
  if (tid < 64) {
    float m = Ms[0][tid], s = Ss[0][tid];
    #pragma unroll
    for (int w = 1; w < 8; ++w) {
      const float om = Ms[w][tid], os = Ss[w][tid];
      const float mn = fmaxf(m, om);
      s = s * exp2f(m - mn) + os * exp2f(om - mn);
      m = mn;
    }
    m_g[(size_t)b * N_ + qb + tid]  = m;
    il_g[(size_t)b * N_ + qb + tid] = 1.0f / s;
  }
}

// ---------------------------------------------------------------------------
// Kernel 3: P-writer.  P[bz][q][m] = exp2(e - m_q) * il_q  (fp16, normalized).
// Block = 64 q x 256 m; MFMA results -> padded LDS -> coalesced 16B stores.
// ---------------------------------------------------------------------------
__global__ __launch_bounds__(256) void pwrite_kernel(
    const _Float16* __restrict__ Qh, const _Float16* __restrict__ Kh,
    const float* __restrict__ m_g, const float* __restrict__ il_g,
    _Float16* __restrict__ P, int b0)
{
  __shared__ _Float16 Pl[64 * 260];

  const int tid = threadIdx.x;
  const int wid = tid >> 6, lane = tid & 63, ln = lane & 15, lh = lane >> 4;
  const int mb = blockIdx.x * 256;
  const int qb = blockIdx.y * 64;
  const int bz = blockIdx.z;
  const int b  = b0 + bz;

  float m_l[4], il_l[4];
  #pragma unroll
  for (int rt = 0; rt < 4; ++rt) {
    m_l[rt]  = m_g [(size_t)b * N_ + qb + rt * 16 + ln];
    il_l[rt] = il_g[(size_t)b * N_ + qb + rt * 16 + ln];
  }

  half8 qf[4][2];
  #pragma unroll
  for (int rt = 0; rt < 4; ++rt)
    #pragma unroll
    for (int h = 0; h < 2; ++h)
      qf[rt][h] = *(const half8*)&Qh[((size_t)b * N_ + qb + rt * 16 + ln) * CQ_ + h * 32 + lh * 8];

  half8 kf[4][2];
  #pragma unroll
  for (int ms = 0; ms < 4; ++ms)
    #pragma unroll
    for (int h = 0; h < 2; ++h)
      kf[ms][h] = *(const half8*)&Kh[((size_t)b * N_ + mb + wid * 64 + ms * 16 + ln) * CQ_ + h * 32 + lh * 8];

  #pragma unroll
  for (int ms = 0; ms < 4; ++ms) {
    #pragma unroll
    for (int rt = 0; rt < 4; ++rt) {
      f32x4 e = {};
      e = __builtin_amdgcn_mfma_f32_16x16x32_f16(kf[ms][0], qf[rt][0], e, 0, 0, 0);
      e = __builtin_amdgcn_mfma_f32_16x16x32_f16(kf[ms][1], qf[rt][1], e, 0, 0, 0);
      half4 pv;
      #pragma unroll
      for (int j = 0; j < 4; ++j)
        pv[j] = (_Float16)(exp2f(e[j] - m_l[rt]) * il_l[rt]);
      *(half4*)&Pl[(rt * 16 + ln) * 260 + wid * 64 + ms * 16 + lh * 4] = pv;
    }
  }
  __syncthreads();

  const int row = tid >> 2;
  const int cb  = (tid & 3) * 8;
  #pragma unroll
  for (int i = 0; i < 8; ++i) {
    half8 v = *(const half8*)&Pl[row * 260 + cb + i * 32];
    *(half8*)&P[((size_t)bz * N_ + qb + row) * N_ + mb + cb + i * 32] = v;
  }
}

// ---------------------------------------------------------------------------
// Kernel 4: PV GEMM, counted-vmcnt triple-buffer (T3+T4) — exact R12 schedule.
// out[b][d][n] = g * (V . P^T) + x.
// Tile 256d x 128n, BK=64, 512 thr (8 waves 4x2; wave = 64d x 64n).
// Per iter: vmcnt(6) -> barrier -> ds_read frags -> stage(t+2) -> 32 MFMAs.
// vmcnt never drains to 0 until the tail.  No setprio (lockstep regime).
// ---------------------------------------------------------------------------
__global__ __launch_bounds__(512) void pv_kernel(
    const float* __restrict__ x, const _Float16* __restrict__ Vh,
    const _Float16* __restrict__ P, const float* __restrict__ gamma,
    float* __restrict__ out, int b0, int nwg)
{
  __shared__ _Float16 As[3][256 * 64];   // 32 KB x3
  __shared__ _Float16 Bs[3][128 * 64];   // 16 KB x3

  const int tid = threadIdx.x;
  const int wid = tid >> 6, lane = tid & 63, ln = lane & 15, lh = lane >> 4;

  const int q8 = nwg >> 3;
  const int wg = (blockIdx.x & 7) * q8 + (blockIdx.x >> 3);
  const int dt = wg & 1;
  const int nt = (wg >> 1) & 31;
  const int bz = wg >> 6;
  const int b  = b0 + bz;
  const int d0 = dt * 256, n0 = nt * 128;

  const _Float16* Ab = Vh + ((size_t)b * C_ + d0) * N_;
  const _Float16* Bb = P  + ((size_t)bz * N_ + n0) * N_;

  const int srow   = lane >> 3;
  const int schunk = lane & 7;
  const _Float16* aSrc[4];
  const _Float16* bSrc[2];
  #pragma unroll
  for (int r = 0; r < 4; ++r) {
    const int row = r * 64 + wid * 8 + srow;
    aSrc[r] = Ab + (size_t)row * N_ + ((schunk ^ (row & 7)) << 3);
  }
  #pragma unroll
  for (int r = 0; r < 2; ++r) {
    const int row = r * 64 + wid * 8 + srow;
    bSrc[r] = Bb + (size_t)row * N_ + ((schunk ^ (row & 7)) << 3);
  }

  auto stage = [&](int buf, int t) {
    const int m0 = t << 6;
    #pragma unroll
    for (int r = 0; r < 4; ++r)
      g2l16(aSrc[r] + m0, (char*)&As[buf][0] + r * 8192 + wid * 1024);
    #pragma unroll
    for (int r = 0; r < 2; ++r)
      g2l16(bSrc[r] + m0, (char*)&Bs[buf][0] + r * 8192 + wid * 1024);
  };

  const int wr = wid >> 1, wc = wid & 1;   // wave = 64d x 64n
  f32x4 acc[4][4] = {};
  const int swl = ln & 7;

  stage(0, 0);
  stage(1, 1);                             // 12 loads in flight

  for (int t = 0; t < 64; ++t) {
    if (t < 63) { asm volatile("s_waitcnt vmcnt(6)" ::: "memory"); }
    else        { asm volatile("s_waitcnt vmcnt(0)" ::: "memory"); }
    __builtin_amdgcn_s_barrier();
    __builtin_amdgcn_sched_barrier(0);

    const int buf = t % 3;
    const _Float16* Ar = &As[buf][0];
    const _Float16* Br = &Bs[buf][0];

    half8 a[4][2], bq[4][2];
    #pragma unroll
    for (int ft = 0; ft < 4; ++ft) {
      const int row = wr * 64 + ft * 16 + ln;
      #pragma unroll
      for (int kk = 0; kk < 2; ++kk)
        a[ft][kk] = *(const half8*)&Ar[row * 64 + ((((kk << 2) | lh) ^ swl) << 3)];
    }
    #pragma unroll
    for (int gt = 0; gt < 4; ++gt) {
      const int row = wc * 64 + gt * 16 + ln;
      #pragma unroll
      for (int kk = 0; kk < 2; ++kk)
        bq[gt][kk] = *(const half8*)&Br[row * 64 + ((((kk << 2) | lh) ^ swl) << 3)];
    }

    if (t < 62) stage((t + 2) % 3, t + 2);   // prefetch 2 ahead

    #pragma unroll
    for (int kk = 0; kk < 2; ++kk)
      #pragma unroll
      for (int ft = 0; ft < 4; ++ft)
        #pragma unroll
        for (int gt = 0; gt < 4; ++gt)
          acc[ft][gt] = __builtin_amdgcn_mfma_f32_16x16x32_f16(a[ft][kk], bq[gt][kk], acc[ft][gt], 0, 0, 0);
  }

  const float g = gamma[0];
  #pragma unroll
  for (int ft = 0; ft < 4; ++ft) {
    #pragma unroll
    for (int gt = 0; gt < 4; ++gt) {
      #pragma unroll
      for (int j = 0; j < 4; ++j) {
        const int d = d0 + wr * 64 + ft * 16 + lh * 4 + j;
        const int n = n0 + wc * 64 + gt * 16 + ln;
        const size_t idx = ((size_t)b * C_ + d) * N_ + n;
        out[idx] = g * acc[ft][gt][j] + x[idx];
      }
    }
  }
}

extern "C" void kernel_launch(void* const* d_in, const int* in_sizes, int n_in,
                              void* d_out, int out_size, void* d_ws, size_t ws_size,
                              hipStream_t stream) {
  const float* x     = (const float*)d_in[0];
  const float* Wq    = (const float*)d_in[1];
  const float* Wk    = (const float*)d_in[2];
  const float* Wv    = (const float*)d_in[3];
  const float* gamma = (const float*)d_in[4];
  float* out = (float*)d_out;

  _Float16* Qh = (_Float16*)d_ws;                        // 2 MB
  _Float16* Kh = Qh + (size_t)B_ * N_ * CQ_;             // 2 MB
  _Float16* Vh = Kh + (size_t)B_ * N_ * CQ_;             // 16.8 MB
  float* m_g   = (float*)(Vh + (size_t)B_ * C_ * N_);    // 64 KB
  float* il_g  = m_g + (size_t)B_ * N_;                  // 64 KB
  _Float16* Wh = (_Float16*)(il_g + (size_t)B_ * N_);    // 0.66 MB
  _Float16* P  = Wh + (size_t)640 * C_;

  const size_t fixed = (size_t)((char*)P - (char*)d_ws);
  const int nb = (ws_size >= fixed + (size_t)B_ * N_ * N_ * sizeof(_Float16)) ? 4 : 2;

  wcvt_kernel<<<dim3(640), 256, 0, stream>>>(Wq, Wk, Wv, Wh);
  proj_kernel<<<dim3(512), 256, 0, stream>>>(x, Wh, Qh, Kh, Vh);
  stats_kernel<<<dim3(256), 512, 0, stream>>>(Qh, Kh, m_g, il_g);

  for (int b0 = 0; b0 < B_; b0 += nb) {
    pwrite_kernel<<<dim3(16, 64, nb), 256, 0, stream>>>(Qh, Kh, m_g, il_g, P, b0);
    pv_kernel<<<dim3(nb * 64), 512, 0, stream>>>(x, Vh, P, gamma, out, b0, nb * 64);
  }
}